// Round 1
// baseline (17929.327 us; speedup 1.0000x reference)
//
#include <hip/hip_runtime.h>
#include <math.h>

// MiniGPT forward, f32 baseline. B=4 T=1024 D=768 H=12 L=4 DFF=3072 V=32000.
// Round-1 goal: correctness + sane dispatch structure for later MFMA upgrade.

#define V_   32000
#define D_   768
#define H_   12
#define L_   4
#define T_   1024
#define B_   4
#define DFF_ 3072
#define BT_  (B_ * T_)
#define HD_  64          // head dim = D/H = 64
#define LN_EPS 1e-5f

// ---------------------------------------------------------------------------
// Embedding: x[b,t,:] = tok_emb[idx[b,t],:] + pos_emb[t,:]
// ---------------------------------------------------------------------------
__global__ __launch_bounds__(256) void embed_k(
    const int* __restrict__ idx, const float* __restrict__ tok,
    const float* __restrict__ pos, float* __restrict__ x) {
  int i = blockIdx.x * 256 + threadIdx.x;
  if (i >= BT_ * D_) return;
  int row = i / D_;
  int d   = i - row * D_;
  int t   = row & (T_ - 1);               // T_ = 1024 (pow2)
  x[i] = tok[(size_t)idx[row] * D_ + d] + pos[t * D_ + d];
}

// ---------------------------------------------------------------------------
// LayerNorm: one 256-thread block per row (D=768 -> 3 elems/thread)
// ---------------------------------------------------------------------------
__global__ __launch_bounds__(256) void ln_k(
    const float* __restrict__ x, const float* __restrict__ g,
    const float* __restrict__ b, float* __restrict__ out) {
  int row = blockIdx.x;
  const float* xr = x + (size_t)row * D_;
  float* orow     = out + (size_t)row * D_;
  int tid = threadIdx.x;

  float s = 0.f, ss = 0.f;
  for (int i = tid; i < D_; i += 256) {
    float t = xr[i];
    s += t; ss += t * t;
  }
  // wave64 reduce
  for (int off = 32; off; off >>= 1) {
    s  += __shfl_xor(s, off, 64);
    ss += __shfl_xor(ss, off, 64);
  }
  __shared__ float sm[2][4];
  int wid = tid >> 6;
  if ((tid & 63) == 0) { sm[0][wid] = s; sm[1][wid] = ss; }
  __syncthreads();
  s  = sm[0][0] + sm[0][1] + sm[0][2] + sm[0][3];
  ss = sm[1][0] + sm[1][1] + sm[1][2] + sm[1][3];

  float mu  = s * (1.f / D_);
  float var = ss * (1.f / D_) - mu * mu;
  float r   = rsqrtf(var + LN_EPS);
  for (int i = tid; i < D_; i += 256)
    orow[i] = (xr[i] - mu) * r * g[i] + b[i];
}

// ---------------------------------------------------------------------------
// Tiled f32 GEMM: C[M,N] = A[M,K] @ B[K,N] (+bias[n]) (relu?) (+residual[m,n])
// 64x64 block tile, BK=16, 16x16 threads, 4x4 per thread.
// All M,N,K here are multiples of 64/16 — no guards.
// ---------------------------------------------------------------------------
#define BM 64
#define BN 64
#define BK 16
__global__ __launch_bounds__(256) void gemm_k(
    const float* __restrict__ A, const float* __restrict__ B,
    const float* __restrict__ bias, const float* __restrict__ residual,
    float* __restrict__ C, int M, int N, int K, int relu) {
  __shared__ float As[BM][BK + 1];   // +1 pad: kills 4-way bank conflict on column reads
  __shared__ float Bs[BK][BN + 1];

  int tid = threadIdx.x;
  int tx  = tid & 15;   // n direction
  int ty  = tid >> 4;   // m direction
  int bn  = blockIdx.x * BN;
  int bm  = blockIdx.y * BM;

  float acc[4][4] = {};

  for (int k0 = 0; k0 < K; k0 += BK) {
    for (int i = tid; i < BM * BK; i += 256) {
      int r = i >> 4, c = i & 15;
      As[r][c] = A[(size_t)(bm + r) * K + k0 + c];
    }
    for (int i = tid; i < BK * BN; i += 256) {
      int r = i >> 6, c = i & 63;
      Bs[r][c] = B[(size_t)(k0 + r) * N + bn + c];
    }
    __syncthreads();
#pragma unroll
    for (int kk = 0; kk < BK; ++kk) {
      float a[4], bb[4];
#pragma unroll
      for (int i = 0; i < 4; ++i) a[i]  = As[ty * 4 + i][kk];
#pragma unroll
      for (int j = 0; j < 4; ++j) bb[j] = Bs[kk][tx * 4 + j];
#pragma unroll
      for (int i = 0; i < 4; ++i)
#pragma unroll
        for (int j = 0; j < 4; ++j)
          acc[i][j] += a[i] * bb[j];
    }
    __syncthreads();
  }

#pragma unroll
  for (int i = 0; i < 4; ++i) {
    int m = bm + ty * 4 + i;
#pragma unroll
    for (int j = 0; j < 4; ++j) {
      int n = bn + tx * 4 + j;
      float v = acc[i][j];
      if (bias)     v += bias[n];
      if (relu)     v  = fmaxf(v, 0.f);
      if (residual) v += residual[(size_t)m * N + n];
      C[(size_t)m * N + n] = v;
    }
  }
}

// ---------------------------------------------------------------------------
// Causal attention, online softmax. One wave (64 threads) per (b,h,t).
// q/k/v are [B*T, D] with head h at columns h*64..h*64+63.
// Lane holds output dim d=lane; scores tile of 64 s-values, one per lane.
// ---------------------------------------------------------------------------
__global__ __launch_bounds__(64) void attn_k(
    const float* __restrict__ q, const float* __restrict__ k,
    const float* __restrict__ v, float* __restrict__ out) {
  int t = blockIdx.x, h = blockIdx.y, b = blockIdx.z;
  int lane = threadIdx.x;
  const float scale = 0.125f;   // 1/sqrt(64)

  __shared__ float qs[64];
  __shared__ float ks[64][65];  // +1 pad: conflict-free column reads
  __shared__ float ps[64];

  size_t qoff = ((size_t)(b * T_ + t) * D_) + h * HD_;
  qs[lane] = q[qoff + lane];
  __syncthreads();

  float m = -INFINITY, l = 0.f, acc = 0.f;

  for (int s0 = 0; s0 <= t; s0 += 64) {
    int ns = min(64, t - s0 + 1);
    // stage K tile: ks[r][:] = k row (s0+r), coalesced
    for (int r = 0; r < ns; ++r)
      ks[r][lane] = k[((size_t)(b * T_ + s0 + r) * D_) + h * HD_ + lane];
    __syncthreads();

    float sc = -INFINITY;
    if (lane < ns) {
      float d = 0.f;
#pragma unroll
      for (int j = 0; j < 64; ++j) d += qs[j] * ks[lane][j];
      sc = d * scale;
    }
    float mt = sc;
    for (int off = 32; off; off >>= 1) mt = fmaxf(mt, __shfl_xor(mt, off, 64));
    float mnew  = fmaxf(m, mt);
    float alpha = expf(m - mnew);          // m=-inf first iter -> 0
    float p     = (lane < ns) ? expf(sc - mnew) : 0.f;

    float pl = p;
    for (int off = 32; off; off >>= 1) pl += __shfl_xor(pl, off, 64);
    l   = l * alpha + pl;
    acc = acc * alpha;

    ps[lane] = p;
    __syncthreads();
    for (int s = 0; s < ns; ++s)
      acc += ps[s] * v[((size_t)(b * T_ + s0 + s) * D_) + h * HD_ + lane];
    __syncthreads();
    m = mnew;
  }

  out[qoff + lane] = acc / l;
}

// ---------------------------------------------------------------------------
// launch
// ---------------------------------------------------------------------------
extern "C" void kernel_launch(void* const* d_in, const int* in_sizes, int n_in,
                              void* d_out, int out_size, void* d_ws, size_t ws_size,
                              hipStream_t stream) {
  const int*   idx   = (const int*)  d_in[0];
  const float* tok   = (const float*)d_in[1];
  const float* pos   = (const float*)d_in[2];
  const float* Wq    = (const float*)d_in[3];
  const float* Wk    = (const float*)d_in[4];
  const float* Wv    = (const float*)d_in[5];
  const float* Wp    = (const float*)d_in[6];
  const float* bp    = (const float*)d_in[7];
  const float* ln1g  = (const float*)d_in[8];
  const float* ln1b  = (const float*)d_in[9];
  const float* ln2g  = (const float*)d_in[10];
  const float* ln2b  = (const float*)d_in[11];
  const float* W1    = (const float*)d_in[12];
  const float* b1    = (const float*)d_in[13];
  const float* W2    = (const float*)d_in[14];
  const float* b2    = (const float*)d_in[15];
  const float* lnfg  = (const float*)d_in[16];
  const float* lnfb  = (const float*)d_in[17];
  const float* Wlm   = (const float*)d_in[18];
  const float* blm   = (const float*)d_in[19];
  float* outp = (float*)d_out;

  // workspace layout (floats): 6*BT*D + BT*DFF = ~126 MB
  float* ws  = (float*)d_ws;
  float* x   = ws;                    // BT*D
  float* xn  = x  + (size_t)BT_ * D_;
  float* q   = xn + (size_t)BT_ * D_;
  float* kk  = q  + (size_t)BT_ * D_;
  float* vv  = kk + (size_t)BT_ * D_;
  float* att = vv + (size_t)BT_ * D_;
  float* h1  = att + (size_t)BT_ * D_;   // BT*DFF

  dim3 g_d(D_ / BN, BT_ / BM);           // 12 x 64
  dim3 g_ff(DFF_ / BN, BT_ / BM);        // 48 x 64
  dim3 g_lm(V_ / BN, BT_ / BM);          // 500 x 64

  embed_k<<<(BT_ * D_ + 255) / 256, 256, 0, stream>>>(idx, tok, pos, x);

  for (int l = 0; l < L_; ++l) {
    const float* wq = Wq + (size_t)l * D_ * D_;
    const float* wk = Wk + (size_t)l * D_ * D_;
    const float* wv = Wv + (size_t)l * D_ * D_;
    const float* wp = Wp + (size_t)l * D_ * D_;
    const float* w1 = W1 + (size_t)l * D_ * DFF_;
    const float* w2 = W2 + (size_t)l * DFF_ * D_;

    ln_k<<<BT_, 256, 0, stream>>>(x, ln1g + l * D_, ln1b + l * D_, xn);
    gemm_k<<<g_d, 256, 0, stream>>>(xn, wq, nullptr, nullptr, q,  BT_, D_, D_, 0);
    gemm_k<<<g_d, 256, 0, stream>>>(xn, wk, nullptr, nullptr, kk, BT_, D_, D_, 0);
    gemm_k<<<g_d, 256, 0, stream>>>(xn, wv, nullptr, nullptr, vv, BT_, D_, D_, 0);
    attn_k<<<dim3(T_, H_, B_), 64, 0, stream>>>(q, kk, vv, att);
    // x = x + att @ Wp + bp   (in-place residual: safe, 1 read + 1 write per elem)
    gemm_k<<<g_d, 256, 0, stream>>>(att, wp, bp + l * D_, x, x, BT_, D_, D_, 0);

    ln_k<<<BT_, 256, 0, stream>>>(x, ln2g + l * D_, ln2b + l * D_, xn);
    gemm_k<<<g_ff, 256, 0, stream>>>(xn, w1, b1 + l * DFF_, nullptr, h1,
                                     BT_, DFF_, D_, 1);
    gemm_k<<<g_d, 256, 0, stream>>>(h1, w2, b2 + l * D_, x, x, BT_, D_, DFF_, 0);
  }

  ln_k<<<BT_, 256, 0, stream>>>(x, lnfg, lnfb, xn);
  gemm_k<<<g_lm, 256, 0, stream>>>(xn, Wlm, blm, nullptr, outp, BT_, V_, D_, 0);
}